// Round 12
// baseline (551.028 us; speedup 1.0000x reference)
//
#include <hip/hip_runtime.h>
#include <hip/hip_bf16.h>
#include <math.h>

#define NGRAPH 64
#define EPSV 1e-6f
#define CH 4096          // edges per partition chunk

__device__ __forceinline__ unsigned enc_f32(float f){
    unsigned u = __float_as_uint(f);
    return (u & 0x80000000u) ? ~u : (u | 0x80000000u);
}
__device__ __forceinline__ float dec_f32(unsigned u){
    return (u & 0x80000000u) ? __uint_as_float(u & 0x7FFFFFFFu) : __uint_as_float(~u);
}
__device__ __forceinline__ unsigned bf16_rn(float x){
    unsigned u = __float_as_uint(x);
    return (u + 0x7fffu + ((u>>16)&1u)) >> 16;
}
__device__ __forceinline__ float bflo(unsigned u){ return __uint_as_float(u<<16); }
__device__ __forceinline__ float bfhi(unsigned u){ return __uint_as_float(u & 0xffff0000u); }

// ---------------- bucket histogram ----------------
__global__ __launch_bounds__(256) void k_hist_c(const int* __restrict__ tgt,
                                                int* __restrict__ bhist,
                                                int E, int shift, int nbuk){
    __shared__ int h[256];
    int t = threadIdx.x;
    h[t] = 0; __syncthreads();
    int blk = blockIdx.x;            // sub-block: 2048 edges
    int chunk = blk >> 1;
    int base = blk*2048;
    int lim  = base + 2048; if(lim > E) lim = E;
    for(int i=base+t; i<lim; i+=256)
        atomicAdd(&h[tgt[i]>>shift], 1);
    __syncthreads();
    if(t < nbuk && h[t]) atomicAdd(&bhist[chunk*nbuk + t], h[t]);
}

__global__ __launch_bounds__(256) void k_btot(const int* __restrict__ bhist, int* __restrict__ btot,
                                              int nchunk, int nbuk){
    __shared__ int red[256];
    int b = blockIdx.x, t = threadIdx.x;
    int s = 0;
    for(int blk=t; blk<nchunk; blk+=256) s += bhist[blk*nbuk + b];
    red[t] = s; __syncthreads();
    for(int off=128; off>0; off>>=1){
        if(t<off) red[t] += red[t+off];
        __syncthreads();
    }
    if(t==0) btot[b] = red[0];
}

__global__ __launch_bounds__(256) void k_bbase0(const int* __restrict__ btot, int* __restrict__ bbase0, int nbuk){
    __shared__ int s[256];
    int t = threadIdx.x;
    int v = (t<nbuk) ? btot[t] : 0;
    s[t] = v; __syncthreads();
    for(int off=1; off<256; off<<=1){
        int a = (t>=off) ? s[t-off] : 0;
        __syncthreads();
        s[t] += a;
        __syncthreads();
    }
    if(t<nbuk) bbase0[t] = s[t] - v;
}

__global__ __launch_bounds__(512) void k_bbase(const int* __restrict__ bhist, const int* __restrict__ bbase0,
                                               int* __restrict__ bbase, int nchunk, int nbuk){
    __shared__ int s[512];
    int b = blockIdx.x, t = threadIdx.x;
    int v = (t<nchunk) ? bhist[t*nbuk + b] : 0;
    s[t] = v; __syncthreads();
    for(int off=1; off<512; off<<=1){
        int a = (t>=off) ? s[t-off] : 0;
        __syncthreads();
        s[t] += a;
        __syncthreads();
    }
    if(t<nchunk) bbase[t*nbuk + b] = bbase0[b] + s[t] - v;
}

// place edges (packed 32-bit: src<<shift | tgt_local) into bucket-ordered ebuf
// via LDS tickets; fused exact layer-0 edge max of e1*e2
__global__ __launch_bounds__(256) void k_place(const int* __restrict__ src, const int* __restrict__ tgt,
                                               const int* __restrict__ bbase, unsigned* __restrict__ ebuf,
                                               const float* __restrict__ e1, const float* __restrict__ e2,
                                               unsigned* __restrict__ amax_enc,
                                               int E, int shift, int nbuk){
    __shared__ int lcur[256];
    __shared__ float wm[4];
    int t = threadIdx.x, blk = blockIdx.x;
    lcur[t] = (t<nbuk) ? bbase[blk*nbuk + t] : 0;
    __syncthreads();
    unsigned msk = (1u<<shift) - 1u;
    int base = blk*CH;
    int lim  = base + CH; if(lim > E) lim = E;
    float m = 0.f;
    for(int i=base+t; i<lim; i+=256){
        int ss = src[i], tt = tgt[i];
        m = fmaxf(m, e1[ss] * e2[tt]);
        int p = atomicAdd(&lcur[tt>>shift], 1);
        ebuf[p] = ((unsigned)ss << shift) | ((unsigned)tt & msk);
    }
    for(int off=32; off>0; off>>=1) m = fmaxf(m, __shfl_xor(m, off));
    if((t&63)==0) wm[t>>6] = m;
    __syncthreads();
    if(t==0){
        float mm = fmaxf(fmaxf(wm[0],wm[1]), fmaxf(wm[2],wm[3]));
        atomicMax(amax_enc, enc_f32(mm));
    }
}

// per-bucket local CSR from packed ebuf
__global__ __launch_bounds__(512) void k_sortb(const unsigned* __restrict__ ebuf,
                                               const int* __restrict__ bbase0, const int* __restrict__ btot,
                                               int* __restrict__ row_start, int* __restrict__ sorted_src,
                                               int N, int E, int shift, int nbuk){
    __shared__ int sc[512];
    int b = blockIdx.x, t = threadIdx.x;
    int ebeg = bbase0[b];
    int eend = ebeg + btot[b];
    int nbeg = b << shift;
    unsigned msk = (1u<<shift) - 1u;
    int nloc = N - nbeg; if(nloc > 512) nloc = 512;
    sc[t] = 0; __syncthreads();
    for(int i=ebeg+t; i<eend; i+=512)
        atomicAdd(&sc[ebuf[i] & msk], 1);
    __syncthreads();
    int v = sc[t];
    for(int off=1; off<512; off<<=1){
        int a = (t>=off) ? sc[t-off] : 0;
        __syncthreads();
        sc[t] += a;
        __syncthreads();
    }
    int pos0 = ebeg + sc[t] - v;
    if(t < nloc) row_start[nbeg + t] = pos0;
    if(b == nbuk-1 && t == 0) row_start[N] = E;
    __syncthreads();
    sc[t] = pos0;
    __syncthreads();
    for(int i=ebeg+t; i<eend; i+=512){
        unsigned w = ebuf[i];
        int p = atomicAdd(&sc[w & msk], 1);
        sorted_src[p] = (int)(w >> shift);
    }
}

// ---------------- node transform ----------------
// FDIV: input rows are undivided layer outputs -> scale by 1/(den[n]+eps*A) on load.
template<int DI, int DO, bool FDIV>
__global__ __launch_bounds__(256) void k_xform(
    const float* __restrict__ x, const float* __restrict__ fw,
    const float* __restrict__ ww,
    unsigned* __restrict__ ubf, float* __restrict__ v,
    float* __restrict__ e1, float* __restrict__ e2,
    const float* __restrict__ den, const unsigned* __restrict__ amax_enc, int N)
{
    constexpr int NSLICE = 2*DO/16;
    constexpr int CP = DO/2;
    int lane = threadIdx.x & 63;
    int wid  = __builtin_amdgcn_readfirstlane(threadIdx.x >> 6);
    int wg   = blockIdx.x*4 + wid;
    int ngroups = (N+63)>>6;
    if(wg >= ngroups*NSLICE) return;
    int slice = wg % NSLICE;
    int group = wg / NSLICE;
    int n  = group*64 + lane;
    bool act = n < N;
    int nn = act ? n : N-1;
    bool uhalf = slice < DO/16;
    int scol = (slice & (DO/16 - 1))*16;
    const float* wp  = fw + (uhalf ? 0 : DI*DO) + scol;
    const float* wwp = ww + (uhalf ? 0 : DI);
    float r = 1.f;
    if(FDIV) r = 1.f/(den[nn] + EPSV*dec_f32(*amax_enc));
    float acc[16];
    #pragma unroll
    for(int j=0;j<16;j++) acc[j]=0.f;
    float p = 0.f;
    #pragma unroll
    for(int k4=0;k4<DI/4;k4++){
        float4 xv = *reinterpret_cast<const float4*>(&x[(size_t)nn*DI + k4*4]);
        if(FDIV){ xv.x*=r; xv.y*=r; xv.z*=r; xv.w*=r; }
        #pragma unroll
        for(int kk=0;kk<4;kk++){
            float xk = (kk==0)?xv.x:(kk==1)?xv.y:(kk==2)?xv.z:xv.w;
            int k = k4*4+kk;
            p = fmaf(xk, wwp[k], p);
            #pragma unroll
            for(int j=0;j<16;j++) acc[j] = fmaf(xk, wp[k*DO + j], acc[j]);
        }
    }
    if(act){
        if(uhalf){
            unsigned pk[8];
            #pragma unroll
            for(int j=0;j<8;j++)
                pk[j] = bf16_rn(acc[2*j]) | (bf16_rn(acc[2*j+1])<<16);
            unsigned* dst = &ubf[(size_t)n*CP + scol/2];
            *reinterpret_cast<uint4*>(dst)   = make_uint4(pk[0],pk[1],pk[2],pk[3]);
            *reinterpret_cast<uint4*>(dst+4) = make_uint4(pk[4],pk[5],pk[6],pk[7]);
        } else {
            #pragma unroll
            for(int j4=0;j4<4;j4++)
                *reinterpret_cast<float4*>(&v[(size_t)n*DO + scol + j4*4]) =
                    make_float4(acc[j4*4],acc[j4*4+1],acc[j4*4+2],acc[j4*4+3]);
        }
        if(scol==0) (uhalf ? e1 : e2)[n] = __expf(p);
    }
}

// ---------------- edge softmax + aggregate: lane = channel PAIR ----------------
// DIV=true  (layer 0): amax known -> divide inline.
// DIV=false: write undivided num (xout) + den[n]; track max edge-p and
//   atomicMax once per wave at kernel end (global A for the consumer's division).
template<int DO, bool DIV>
__global__ __launch_bounds__(256) void k_aggregate2(
    const int* __restrict__ row_start, const int* __restrict__ sorted_src,
    const unsigned* __restrict__ ubf, const float* __restrict__ v,
    const float* __restrict__ e1, const float* __restrict__ e2,
    const float* __restrict__ fb,
    unsigned* __restrict__ amax_enc,
    float* __restrict__ den_out,
    float* __restrict__ xout, int N)
{
    constexpr int CP = DO/2;
    constexpr int PN = 64/CP;
    float epsA = 0.f;
    if(DIV) epsA = EPSV * dec_f32(*amax_enc);
    int lane = threadIdx.x & 63;
    int wid  = threadIdx.x >> 6;
    int c2   = lane & (CP-1);
    int grp  = lane >> (CP==32 ? 5 : 4);
    float fx = fb[2*c2], fy = fb[2*c2+1];
    int gw = blockIdx.x*4 + wid;
    int nwaves = gridDim.x*4;
    float gm = 0.f;
    for(int n=gw; n<N; n+=nwaves){
        float2 vv = *reinterpret_cast<const float2*>(&v[(size_t)n*DO + 2*c2]);
        float wx = vv.x + fx, wy = vv.y + fy;
        float e2n = e2[n];
        int beg = row_start[n], end = row_start[n+1];
        float ax = 0.f, ay = 0.f, den = 0.f, pm = 0.f;
        int idx = beg + grp;
        for(; idx + 7*PN < end; idx += 8*PN){
            int s_[8]; float e_[8]; unsigned u_[8];
            #pragma unroll
            for(int q=0;q<8;q++) s_[q] = sorted_src[idx+q*PN];
            #pragma unroll
            for(int q=0;q<8;q++){ e_[q] = e1[s_[q]]; u_[q] = ubf[(size_t)s_[q]*CP+c2]; }
            #pragma unroll
            for(int q=0;q<8;q++){
                float p = e_[q]*e2n;
                den += p;
                if(!DIV) pm = fmaxf(pm, p);
                ax = fmaf(p, fmaxf(bflo(u_[q])+wx,0.f), ax);
                ay = fmaf(p, fmaxf(bfhi(u_[q])+wy,0.f), ay);
            }
        }
        for(; idx + 3*PN < end; idx += 4*PN){
            int s_[4]; float e_[4]; unsigned u_[4];
            #pragma unroll
            for(int q=0;q<4;q++) s_[q] = sorted_src[idx+q*PN];
            #pragma unroll
            for(int q=0;q<4;q++){ e_[q] = e1[s_[q]]; u_[q] = ubf[(size_t)s_[q]*CP+c2]; }
            #pragma unroll
            for(int q=0;q<4;q++){
                float p = e_[q]*e2n;
                den += p;
                if(!DIV) pm = fmaxf(pm, p);
                ax = fmaf(p, fmaxf(bflo(u_[q])+wx,0.f), ax);
                ay = fmaf(p, fmaxf(bfhi(u_[q])+wy,0.f), ay);
            }
        }
        for(; idx < end; idx += PN){
            int s = sorted_src[idx];
            float e = e1[s];
            unsigned uu = ubf[(size_t)s*CP+c2];
            float p = e*e2n;
            den += p;
            if(!DIV) pm = fmaxf(pm, p);
            ax = fmaf(p, fmaxf(bflo(uu)+wx,0.f), ax);
            ay = fmaf(p, fmaxf(bfhi(uu)+wy,0.f), ay);
        }
        #pragma unroll
        for(int off=CP; off<64; off<<=1){
            den += __shfl_xor(den, off);
            ax  += __shfl_xor(ax , off);
            ay  += __shfl_xor(ay , off);
            if(!DIV) pm = fmaxf(pm, __shfl_xor(pm, off));
        }
        if(DIV){
            if(lane < CP){
                float d = den + epsA;
                *reinterpret_cast<float2*>(&xout[(size_t)n*DO + 2*c2]) =
                    make_float2(ax/d, ay/d);
            }
        } else {
            if(lane < CP)
                *reinterpret_cast<float2*>(&xout[(size_t)n*DO + 2*c2]) =
                    make_float2(ax, ay);
            if(lane == 0) den_out[n] = den;
            gm = fmaxf(gm, pm);
        }
    }
    if(!DIV && lane == 0) atomicMax(amax_enc, enc_f32(gm));
}

// ---------------- graph pooling (fused final division) ----------------
__global__ __launch_bounds__(512) void k_pool1(const float* __restrict__ x, const int* __restrict__ gid,
                                               const float* __restrict__ den, const unsigned* __restrict__ amax_enc,
                                               float* __restrict__ gpart, int N){
    __shared__ float bins[64*64];
    float epsA = EPSV * dec_f32(*amax_enc);
    int t = threadIdx.x;
    for(int i=t;i<4096;i+=512) bins[i]=0.f;
    __syncthreads();
    int lane = t & 63, wid = t>>6;
    int gw = blockIdx.x*8 + wid;
    int nwaves = gridDim.x*8;
    for(int n=gw; n<N; n+=nwaves){
        int gi = gid[n];
        float r = 1.f/(den[n] + epsA);
        atomicAdd(&bins[gi*64 + lane], x[(size_t)n*64 + lane]*r);
    }
    __syncthreads();
    float* dst = &gpart[(size_t)blockIdx.x*4096];
    for(int i=t;i<4096;i+=512) dst[i] = bins[i];
}

__global__ __launch_bounds__(256) void k_pool2(const float* __restrict__ gpart, float* __restrict__ g, int nblk){
    int i = blockIdx.x*256 + threadIdx.x;   // i < 4096
    float s0=0.f, s1=0.f, s2=0.f, s3=0.f;
    int k=0;
    for(; k+3<nblk; k+=4){
        s0 += gpart[(size_t)k*4096+i];
        s1 += gpart[(size_t)(k+1)*4096+i];
        s2 += gpart[(size_t)(k+2)*4096+i];
        s3 += gpart[(size_t)(k+3)*4096+i];
    }
    for(; k<nblk; k++) s0 += gpart[(size_t)k*4096+i];
    g[i] = (s0+s1)+(s2+s3);
}

// ---------------- tiny MLP head ----------------
__global__ __launch_bounds__(1024) void k_mlp(const float* __restrict__ g,
        const float* __restrict__ mw0, const float* __restrict__ mb0,
        const float* __restrict__ mw1, const float* __restrict__ mb1,
        float* __restrict__ out){
    __shared__ float lg[64*64];
    __shared__ float hid[64*32];
    int t = threadIdx.x;
    for(int i=t;i<4096;i+=1024) lg[i]=g[i];
    __syncthreads();
    for(int i=t;i<2048;i+=1024){
        int r = i>>5, h = i&31;
        float a = mb0[h];
        for(int k=0;k<64;k++) a = fmaf(lg[r*64+k], mw0[k*32+h], a);
        hid[i] = fmaxf(a, 0.f);
    }
    __syncthreads();
    for(int i=t;i<640;i+=1024){
        int r = i/10, j = i%10;
        float a = mb1[j];
        for(int h=0;h<32;h++) a = fmaf(hid[r*32+h], mw1[h*10+j], a);
        out[i] = a;
    }
}

extern "C" void kernel_launch(void* const* d_in, const int* in_sizes, int n_in,
                              void* d_out, int out_size, void* d_ws, size_t ws_size,
                              hipStream_t stream){
    const float* x   = (const float*)d_in[0];
    const int*   src = (const int*)d_in[1];
    const int*   tgt = (const int*)d_in[2];
    const int*   gid = (const int*)d_in[3];
    const float* fw[3] = {(const float*)d_in[4],  (const float*)d_in[8],  (const float*)d_in[12]};
    const float* fb[3] = {(const float*)d_in[5],  (const float*)d_in[9],  (const float*)d_in[13]};
    const float* ww[3] = {(const float*)d_in[6],  (const float*)d_in[10], (const float*)d_in[14]};
    const float* mw0 = (const float*)d_in[16];
    const float* mb0 = (const float*)d_in[17];
    const float* mw1 = (const float*)d_in[18];
    const float* mb1 = (const float*)d_in[19];
    float* out = (float*)d_out;

    const int N = in_sizes[3];
    const int E = in_sizes[1];
    const int NG = (N + 63)/64;
    const int NCHUNK = (E + CH - 1)/CH;
    const int NPOOL = 512;
    int shift = 0;
    while(((N-1)>>shift) >= 256) shift++;        // 512 nodes/bucket, nbuk<=256
    const int nbuk = ((N-1)>>shift) + 1;

    char* ws = (char*)d_ws;
    size_t off = 0;
    auto alloc = [&](size_t bytes)->char*{
        char* p = ws + off;
        off += (bytes + 255) & ~(size_t)255;
        return p;
    };
    int*      row_start  = (int*)     alloc((size_t)(N+1)*4);
    int*      sorted_src = (int*)     alloc((size_t)E*4);
    unsigned* ebuf       = (unsigned*)alloc((size_t)E*4);
    float*    e1         = (float*)   alloc((size_t)N*4);
    float*    e2         = (float*)   alloc((size_t)N*4);
    float*    den        = (float*)   alloc((size_t)N*4);
    unsigned* ubf        = (unsigned*)alloc((size_t)N*32*4);
    float*    v          = (float*)   alloc((size_t)N*64*4);
    float*    xA         = (float*)   alloc((size_t)N*64*4);
    float*    xB         = (float*)   alloc((size_t)N*64*4);
    unsigned* amax       = (unsigned*)alloc(3*4);
    float*    g          = (float*)   alloc(4096*4);
    float*    gpart      = (float*)   alloc((size_t)NPOOL*4096*4);
    int*      bhist      = (int*)     alloc((size_t)NCHUNK*nbuk*4);
    int*      btot       = (int*)     alloc(256*4);
    int*      bbase0     = (int*)     alloc(256*4);
    int*      bbase      = (int*)     alloc((size_t)NCHUNK*nbuk*4);

    hipMemsetAsync(amax,  0, 12, stream);
    hipMemsetAsync(bhist, 0, (size_t)NCHUNK*nbuk*4, stream);

    // layer-0 transform first: e1/e2 ready for fused edge-max inside k_place
    k_xform<64,32,false><<<(NG*4+3)/4,256,0,stream>>>(x, fw[0], ww[0], ubf, v, e1, e2, nullptr, nullptr, N);

    k_hist_c <<<NCHUNK*2,256,0,stream>>>(tgt, bhist, E, shift, nbuk);
    k_btot   <<<nbuk,256,0,stream>>>(bhist, btot, NCHUNK, nbuk);
    k_bbase0 <<<1,   256,0,stream>>>(btot, bbase0, nbuk);
    k_bbase  <<<nbuk,512,0,stream>>>(bhist, bbase0, bbase, NCHUNK, nbuk);
    k_place  <<<NCHUNK,256,0,stream>>>(src, tgt, bbase, ebuf, e1, e2, &amax[0], E, shift, nbuk);
    k_sortb  <<<nbuk,512,0,stream>>>(ebuf, bbase0, btot, row_start, sorted_src, N, E, shift, nbuk);

    // layer 0: amax known (k_place) -> divide inline
    k_aggregate2<32,true><<<2048,256,0,stream>>>(row_start, sorted_src, ubf, v, e1, e2, fb[0],
                                                 &amax[0], nullptr, xA, N);
    // layer 1: 32 -> 64 ; division deferred into layer-2 xform
    k_xform<32,64,false><<<(NG*8+3)/4,256,0,stream>>>(xA, fw[1], ww[1], ubf, v, e1, e2, nullptr, nullptr, N);
    k_aggregate2<64,false><<<2048,256,0,stream>>>(row_start, sorted_src, ubf, v, e1, e2, fb[1],
                                                  &amax[1], den, xB, N);
    // layer 2: 64 -> 64 ; xform consumes undivided xB with den/amax[1]
    k_xform<64,64,true><<<(NG*8+3)/4,256,0,stream>>>(xB, fw[2], ww[2], ubf, v, e1, e2, den, &amax[1], N);
    k_aggregate2<64,false><<<2048,256,0,stream>>>(row_start, sorted_src, ubf, v, e1, e2, fb[2],
                                                  &amax[2], den, xA, N);

    // pool consumes undivided xA with den/amax[2]
    k_pool1<<<NPOOL,512,0,stream>>>(xA, gid, den, &amax[2], gpart, N);
    k_pool2<<<16,  256,0,stream>>>(gpart, g, NPOOL);
    k_mlp  <<<1,  1024,0,stream>>>(g, mw0, mb0, mw1, mb1, out);
}

// Round 13
// 395.035 us; speedup vs baseline: 1.3949x; 1.3949x over previous
//
#include <hip/hip_runtime.h>
#include <hip/hip_bf16.h>
#include <math.h>

#define NGRAPH 64
#define EPSV 1e-6f
#define CH 4096          // edges per partition chunk

__device__ __forceinline__ unsigned enc_f32(float f){
    unsigned u = __float_as_uint(f);
    return (u & 0x80000000u) ? ~u : (u | 0x80000000u);
}
__device__ __forceinline__ float dec_f32(unsigned u){
    return (u & 0x80000000u) ? __uint_as_float(u & 0x7FFFFFFFu) : __uint_as_float(~u);
}
__device__ __forceinline__ unsigned bf16_rn(float x){
    unsigned u = __float_as_uint(x);
    return (u + 0x7fffu + ((u>>16)&1u)) >> 16;
}
__device__ __forceinline__ float bflo(unsigned u){ return __uint_as_float(u<<16); }
__device__ __forceinline__ float bfhi(unsigned u){ return __uint_as_float(u & 0xffff0000u); }

// ---------------- bucket histogram ----------------
__global__ __launch_bounds__(256) void k_hist_c(const int* __restrict__ tgt,
                                                int* __restrict__ bhist,
                                                int E, int shift, int nbuk){
    __shared__ int h[256];
    int t = threadIdx.x;
    h[t] = 0; __syncthreads();
    int blk = blockIdx.x;            // sub-block: 2048 edges
    int chunk = blk >> 1;
    int base = blk*2048;
    int lim  = base + 2048; if(lim > E) lim = E;
    for(int i=base+t; i<lim; i+=256)
        atomicAdd(&h[tgt[i]>>shift], 1);
    __syncthreads();
    if(t < nbuk && h[t]) atomicAdd(&bhist[chunk*nbuk + t], h[t]);
}

__global__ __launch_bounds__(256) void k_btot(const int* __restrict__ bhist, int* __restrict__ btot,
                                              int nchunk, int nbuk){
    __shared__ int red[256];
    int b = blockIdx.x, t = threadIdx.x;
    int s = 0;
    for(int blk=t; blk<nchunk; blk+=256) s += bhist[blk*nbuk + b];
    red[t] = s; __syncthreads();
    for(int off=128; off>0; off>>=1){
        if(t<off) red[t] += red[t+off];
        __syncthreads();
    }
    if(t==0) btot[b] = red[0];
}

__global__ __launch_bounds__(256) void k_bbase0(const int* __restrict__ btot, int* __restrict__ bbase0, int nbuk){
    __shared__ int s[256];
    int t = threadIdx.x;
    int v = (t<nbuk) ? btot[t] : 0;
    s[t] = v; __syncthreads();
    for(int off=1; off<256; off<<=1){
        int a = (t>=off) ? s[t-off] : 0;
        __syncthreads();
        s[t] += a;
        __syncthreads();
    }
    if(t<nbuk) bbase0[t] = s[t] - v;
}

__global__ __launch_bounds__(512) void k_bbase(const int* __restrict__ bhist, const int* __restrict__ bbase0,
                                               int* __restrict__ bbase, int nchunk, int nbuk){
    __shared__ int s[512];
    int b = blockIdx.x, t = threadIdx.x;
    int v = (t<nchunk) ? bhist[t*nbuk + b] : 0;
    s[t] = v; __syncthreads();
    for(int off=1; off<512; off<<=1){
        int a = (t>=off) ? s[t-off] : 0;
        __syncthreads();
        s[t] += a;
        __syncthreads();
    }
    if(t<nchunk) bbase[t*nbuk + b] = bbase0[b] + s[t] - v;
}

// place edges into bucket-ordered ebuf via LDS tickets; fused exact layer-0 edge max
__global__ __launch_bounds__(256) void k_place(const int* __restrict__ src, const int* __restrict__ tgt,
                                               const int* __restrict__ bbase, int2* __restrict__ ebuf,
                                               const float* __restrict__ e1, const float* __restrict__ e2,
                                               unsigned* __restrict__ amax_enc,
                                               int E, int shift, int nbuk){
    __shared__ int lcur[256];
    __shared__ float wm[4];
    int t = threadIdx.x, blk = blockIdx.x;
    lcur[t] = (t<nbuk) ? bbase[blk*nbuk + t] : 0;
    __syncthreads();
    int base = blk*CH;
    int lim  = base + CH; if(lim > E) lim = E;
    float m = 0.f;
    for(int i=base+t; i<lim; i+=256){
        int ss = src[i], tt = tgt[i];
        m = fmaxf(m, e1[ss] * e2[tt]);
        int p = atomicAdd(&lcur[tt>>shift], 1);
        ebuf[p] = make_int2(ss, tt);
    }
    for(int off=32; off>0; off>>=1) m = fmaxf(m, __shfl_xor(m, off));
    if((t&63)==0) wm[t>>6] = m;
    __syncthreads();
    if(t==0){
        float mm = fmaxf(fmaxf(wm[0],wm[1]), fmaxf(wm[2],wm[3]));
        atomicMax(amax_enc, enc_f32(mm));
    }
}

// per-bucket local CSR
__global__ __launch_bounds__(512) void k_sortb(const int2* __restrict__ ebuf,
                                               const int* __restrict__ bbase0, const int* __restrict__ btot,
                                               int* __restrict__ row_start, int* __restrict__ sorted_src,
                                               int N, int E, int shift, int nbuk){
    __shared__ int sc[512];
    int b = blockIdx.x, t = threadIdx.x;
    int ebeg = bbase0[b];
    int eend = ebeg + btot[b];
    int nbeg = b << shift;
    int nloc = N - nbeg; if(nloc > 512) nloc = 512;
    sc[t] = 0; __syncthreads();
    for(int i=ebeg+t; i<eend; i+=512)
        atomicAdd(&sc[ebuf[i].y - nbeg], 1);
    __syncthreads();
    int v = sc[t];
    for(int off=1; off<512; off<<=1){
        int a = (t>=off) ? sc[t-off] : 0;
        __syncthreads();
        sc[t] += a;
        __syncthreads();
    }
    int pos0 = ebeg + sc[t] - v;
    if(t < nloc) row_start[nbeg + t] = pos0;
    if(b == nbuk-1 && t == 0) row_start[N] = E;
    __syncthreads();
    sc[t] = pos0;
    __syncthreads();
    for(int i=ebeg+t; i<eend; i+=512){
        int2 e = ebuf[i];
        int p = atomicAdd(&sc[e.y - nbeg], 1);
        sorted_src[p] = e.x;
    }
}

// ---------------- node transform ----------------
template<int DI, int DO>
__global__ __launch_bounds__(256) void k_xform(
    const float* __restrict__ x, const float* __restrict__ fw,
    const float* __restrict__ ww,
    unsigned* __restrict__ ubf, float* __restrict__ v,
    float* __restrict__ e1, float* __restrict__ e2, int N)
{
    constexpr int NSLICE = 2*DO/16;
    constexpr int CP = DO/2;
    int lane = threadIdx.x & 63;
    int wid  = __builtin_amdgcn_readfirstlane(threadIdx.x >> 6);
    int wg   = blockIdx.x*4 + wid;
    int ngroups = (N+63)>>6;
    if(wg >= ngroups*NSLICE) return;
    int slice = wg % NSLICE;
    int group = wg / NSLICE;
    int n  = group*64 + lane;
    bool act = n < N;
    int nn = act ? n : N-1;
    bool uhalf = slice < DO/16;
    int scol = (slice & (DO/16 - 1))*16;
    const float* wp  = fw + (uhalf ? 0 : DI*DO) + scol;
    const float* wwp = ww + (uhalf ? 0 : DI);
    float acc[16];
    #pragma unroll
    for(int j=0;j<16;j++) acc[j]=0.f;
    float p = 0.f;
    #pragma unroll
    for(int k4=0;k4<DI/4;k4++){
        float4 xv = *reinterpret_cast<const float4*>(&x[(size_t)nn*DI + k4*4]);
        #pragma unroll
        for(int kk=0;kk<4;kk++){
            float xk = (kk==0)?xv.x:(kk==1)?xv.y:(kk==2)?xv.z:xv.w;
            int k = k4*4+kk;
            p = fmaf(xk, wwp[k], p);
            #pragma unroll
            for(int j=0;j<16;j++) acc[j] = fmaf(xk, wp[k*DO + j], acc[j]);
        }
    }
    if(act){
        if(uhalf){
            unsigned pk[8];
            #pragma unroll
            for(int j=0;j<8;j++)
                pk[j] = bf16_rn(acc[2*j]) | (bf16_rn(acc[2*j+1])<<16);
            unsigned* dst = &ubf[(size_t)n*CP + scol/2];
            *reinterpret_cast<uint4*>(dst)   = make_uint4(pk[0],pk[1],pk[2],pk[3]);
            *reinterpret_cast<uint4*>(dst+4) = make_uint4(pk[4],pk[5],pk[6],pk[7]);
        } else {
            #pragma unroll
            for(int j4=0;j4<4;j4++)
                *reinterpret_cast<float4*>(&v[(size_t)n*DO + scol + j4*4]) =
                    make_float4(acc[j4*4],acc[j4*4+1],acc[j4*4+2],acc[j4*4+3]);
        }
        if(scol==0) (uhalf ? e1 : e2)[n] = __expf(p);
    }
}

// ---------------- edge softmax + aggregate: lane = channel PAIR ----------------
// DIV=true  (layer 0): amax already known -> divide inline.
// DIV=false (layers 1,2): write num (xout), den[n], pmax[n]; k_amax reduces
//   the exact global edge-max A = max_n pmax[n]; division deferred to consumer.
template<int DO, bool DIV>
__global__ __launch_bounds__(256) void k_aggregate2(
    const int* __restrict__ row_start, const int* __restrict__ sorted_src,
    const unsigned* __restrict__ ubf, const float* __restrict__ v,
    const float* __restrict__ e1, const float* __restrict__ e2,
    const float* __restrict__ fb,
    const unsigned* __restrict__ amax_enc,
    float* __restrict__ den_out, float* __restrict__ pmax_out,
    float* __restrict__ xout, int N)
{
    constexpr int CP = DO/2;
    constexpr int PN = 64/CP;
    float epsA = 0.f;
    if(DIV) epsA = EPSV * dec_f32(*amax_enc);
    int lane = threadIdx.x & 63;
    int wid  = threadIdx.x >> 6;
    int c2   = lane & (CP-1);
    int grp  = lane >> (CP==32 ? 5 : 4);
    float fx = fb[2*c2], fy = fb[2*c2+1];
    int gw = blockIdx.x*4 + wid;
    int nwaves = gridDim.x*4;
    for(int n=gw; n<N; n+=nwaves){
        float2 vv = *reinterpret_cast<const float2*>(&v[(size_t)n*DO + 2*c2]);
        float wx = vv.x + fx, wy = vv.y + fy;
        float e2n = e2[n];
        int beg = row_start[n], end = row_start[n+1];
        float ax = 0.f, ay = 0.f, den = 0.f, pm = 0.f;
        int idx = beg + grp;
        for(; idx + 7*PN < end; idx += 8*PN){
            int s_[8]; float e_[8]; unsigned u_[8];
            #pragma unroll
            for(int q=0;q<8;q++) s_[q] = sorted_src[idx+q*PN];
            #pragma unroll
            for(int q=0;q<8;q++){ e_[q] = e1[s_[q]]; u_[q] = ubf[(size_t)s_[q]*CP+c2]; }
            #pragma unroll
            for(int q=0;q<8;q++){
                float p = e_[q]*e2n;
                den += p;
                if(!DIV) pm = fmaxf(pm, p);
                ax = fmaf(p, fmaxf(bflo(u_[q])+wx,0.f), ax);
                ay = fmaf(p, fmaxf(bfhi(u_[q])+wy,0.f), ay);
            }
        }
        for(; idx + 3*PN < end; idx += 4*PN){
            int s_[4]; float e_[4]; unsigned u_[4];
            #pragma unroll
            for(int q=0;q<4;q++) s_[q] = sorted_src[idx+q*PN];
            #pragma unroll
            for(int q=0;q<4;q++){ e_[q] = e1[s_[q]]; u_[q] = ubf[(size_t)s_[q]*CP+c2]; }
            #pragma unroll
            for(int q=0;q<4;q++){
                float p = e_[q]*e2n;
                den += p;
                if(!DIV) pm = fmaxf(pm, p);
                ax = fmaf(p, fmaxf(bflo(u_[q])+wx,0.f), ax);
                ay = fmaf(p, fmaxf(bfhi(u_[q])+wy,0.f), ay);
            }
        }
        for(; idx < end; idx += PN){
            int s = sorted_src[idx];
            float e = e1[s];
            unsigned uu = ubf[(size_t)s*CP+c2];
            float p = e*e2n;
            den += p;
            if(!DIV) pm = fmaxf(pm, p);
            ax = fmaf(p, fmaxf(bflo(uu)+wx,0.f), ax);
            ay = fmaf(p, fmaxf(bfhi(uu)+wy,0.f), ay);
        }
        #pragma unroll
        for(int off=CP; off<64; off<<=1){
            den += __shfl_xor(den, off);
            ax  += __shfl_xor(ax , off);
            ay  += __shfl_xor(ay , off);
            if(!DIV) pm = fmaxf(pm, __shfl_xor(pm, off));
        }
        if(DIV){
            if(lane < CP){
                float d = den + epsA;
                *reinterpret_cast<float2*>(&xout[(size_t)n*DO + 2*c2]) =
                    make_float2(ax/d, ay/d);
            }
        } else {
            if(lane < CP)
                *reinterpret_cast<float2*>(&xout[(size_t)n*DO + 2*c2]) =
                    make_float2(ax, ay);
            if(lane == 0){ den_out[n] = den; pmax_out[n] = pm; }
        }
    }
}

// reduce max over pmax[N] -> amax_enc
__global__ __launch_bounds__(256) void k_amax(const float* __restrict__ pmax,
                                              unsigned* __restrict__ amax_enc, int N){
    __shared__ float wm[4];
    float m = 0.f;
    for(int i = blockIdx.x*256 + threadIdx.x; i<N; i += gridDim.x*256)
        m = fmaxf(m, pmax[i]);
    for(int off=32; off>0; off>>=1) m = fmaxf(m, __shfl_xor(m, off));
    if((threadIdx.x&63)==0) wm[threadIdx.x>>6] = m;
    __syncthreads();
    if(threadIdx.x==0)
        atomicMax(amax_enc, enc_f32(fmaxf(fmaxf(wm[0],wm[1]), fmaxf(wm[2],wm[3]))));
}

// xout[n][*] /= (den[n] + eps*A)   (DO=64: 16 float4 per node)
__global__ __launch_bounds__(256) void k_div(float* __restrict__ x, const float* __restrict__ den,
                                             const unsigned* __restrict__ amax_enc, int N){
    float epsA = EPSV * dec_f32(*amax_enc);
    int tot = N*16;
    int i = blockIdx.x*256 + threadIdx.x;
    int stride = gridDim.x*256;
    float4* xp = reinterpret_cast<float4*>(x);
    for(; i<tot; i+=stride){
        int n = i>>4;
        float r = 1.f/(den[n] + epsA);
        float4 t = xp[i];
        t.x*=r; t.y*=r; t.z*=r; t.w*=r;
        xp[i] = t;
    }
}

// ---------------- graph pooling (fused layer-2 division on load) ----------------
__global__ __launch_bounds__(512) void k_pool1(const float* __restrict__ x, const int* __restrict__ gid,
                                               const float* __restrict__ den, const unsigned* __restrict__ amax_enc,
                                               float* __restrict__ gpart, int N){
    __shared__ float bins[64*64];
    float epsA = EPSV * dec_f32(*amax_enc);
    int t = threadIdx.x;
    for(int i=t;i<4096;i+=512) bins[i]=0.f;
    __syncthreads();
    int lane = t & 63, wid = t>>6;
    int gw = blockIdx.x*8 + wid;
    int nwaves = gridDim.x*8;
    for(int n=gw; n<N; n+=nwaves){
        int gi = gid[n];
        float r = 1.f/(den[n] + epsA);
        atomicAdd(&bins[gi*64 + lane], x[(size_t)n*64 + lane]*r);
    }
    __syncthreads();
    float* dst = &gpart[(size_t)blockIdx.x*4096];
    for(int i=t;i<4096;i+=512) dst[i] = bins[i];
}

__global__ __launch_bounds__(256) void k_pool2(const float* __restrict__ gpart, float* __restrict__ g, int nblk){
    int i = blockIdx.x*256 + threadIdx.x;   // i < 4096
    float s0=0.f, s1=0.f, s2=0.f, s3=0.f;
    int k=0;
    for(; k+3<nblk; k+=4){
        s0 += gpart[(size_t)k*4096+i];
        s1 += gpart[(size_t)(k+1)*4096+i];
        s2 += gpart[(size_t)(k+2)*4096+i];
        s3 += gpart[(size_t)(k+3)*4096+i];
    }
    for(; k<nblk; k++) s0 += gpart[(size_t)k*4096+i];
    g[i] = (s0+s1)+(s2+s3);
}

// ---------------- tiny MLP head ----------------
__global__ __launch_bounds__(1024) void k_mlp(const float* __restrict__ g,
        const float* __restrict__ mw0, const float* __restrict__ mb0,
        const float* __restrict__ mw1, const float* __restrict__ mb1,
        float* __restrict__ out){
    __shared__ float lg[64*64];
    __shared__ float hid[64*32];
    int t = threadIdx.x;
    for(int i=t;i<4096;i+=1024) lg[i]=g[i];
    __syncthreads();
    for(int i=t;i<2048;i+=1024){
        int r = i>>5, h = i&31;
        float a = mb0[h];
        for(int k=0;k<64;k++) a = fmaf(lg[r*64+k], mw0[k*32+h], a);
        hid[i] = fmaxf(a, 0.f);
    }
    __syncthreads();
    for(int i=t;i<640;i+=1024){
        int r = i/10, j = i%10;
        float a = mb1[j];
        for(int h=0;h<32;h++) a = fmaf(hid[r*32+h], mw1[h*10+j], a);
        out[i] = a;
    }
}

extern "C" void kernel_launch(void* const* d_in, const int* in_sizes, int n_in,
                              void* d_out, int out_size, void* d_ws, size_t ws_size,
                              hipStream_t stream){
    const float* x   = (const float*)d_in[0];
    const int*   src = (const int*)d_in[1];
    const int*   tgt = (const int*)d_in[2];
    const int*   gid = (const int*)d_in[3];
    const float* fw[3] = {(const float*)d_in[4],  (const float*)d_in[8],  (const float*)d_in[12]};
    const float* fb[3] = {(const float*)d_in[5],  (const float*)d_in[9],  (const float*)d_in[13]};
    const float* ww[3] = {(const float*)d_in[6],  (const float*)d_in[10], (const float*)d_in[14]};
    const float* mw0 = (const float*)d_in[16];
    const float* mb0 = (const float*)d_in[17];
    const float* mw1 = (const float*)d_in[18];
    const float* mb1 = (const float*)d_in[19];
    float* out = (float*)d_out;

    const int N = in_sizes[3];
    const int E = in_sizes[1];
    const int NG = (N + 63)/64;
    const int NCHUNK = (E + CH - 1)/CH;
    const int NPOOL = 512;
    int shift = 0;
    while(((N-1)>>shift) >= 256) shift++;        // 512 nodes/bucket, nbuk<=256
    const int nbuk = ((N-1)>>shift) + 1;

    char* ws = (char*)d_ws;
    size_t off = 0;
    auto alloc = [&](size_t bytes)->char*{
        char* p = ws + off;
        off += (bytes + 255) & ~(size_t)255;
        return p;
    };
    int*      row_start  = (int*)     alloc((size_t)(N+1)*4);
    int*      sorted_src = (int*)     alloc((size_t)E*4);
    int2*     ebuf       = (int2*)    alloc((size_t)E*8);
    float*    e1         = (float*)   alloc((size_t)N*4);
    float*    e2         = (float*)   alloc((size_t)N*4);
    float*    den        = (float*)   alloc((size_t)N*4);
    float*    pmax       = (float*)   alloc((size_t)N*4);
    unsigned* ubf        = (unsigned*)alloc((size_t)N*32*4);
    float*    v          = (float*)   alloc((size_t)N*64*4);
    float*    xA         = (float*)   alloc((size_t)N*64*4);
    float*    xB         = (float*)   alloc((size_t)N*64*4);
    unsigned* amax       = (unsigned*)alloc(3*4);
    float*    g          = (float*)   alloc(4096*4);
    float*    gpart      = (float*)   alloc((size_t)NPOOL*4096*4);
    int*      bhist      = (int*)     alloc((size_t)NCHUNK*nbuk*4);
    int*      btot       = (int*)     alloc(256*4);
    int*      bbase0     = (int*)     alloc(256*4);
    int*      bbase      = (int*)     alloc((size_t)NCHUNK*nbuk*4);

    hipMemsetAsync(amax,  0, 12, stream);
    hipMemsetAsync(bhist, 0, (size_t)NCHUNK*nbuk*4, stream);

    // layer-0 transform first: e1/e2 ready for fused edge-max inside k_place
    k_xform<64,32><<<(NG*4+3)/4,256,0,stream>>>(x, fw[0], ww[0], ubf, v, e1, e2, N);

    k_hist_c <<<NCHUNK*2,256,0,stream>>>(tgt, bhist, E, shift, nbuk);
    k_btot   <<<nbuk,256,0,stream>>>(bhist, btot, NCHUNK, nbuk);
    k_bbase0 <<<1,   256,0,stream>>>(btot, bbase0, nbuk);
    k_bbase  <<<nbuk,512,0,stream>>>(bhist, bbase0, bbase, NCHUNK, nbuk);
    k_place  <<<NCHUNK,256,0,stream>>>(src, tgt, bbase, ebuf, e1, e2, &amax[0], E, shift, nbuk);
    k_sortb  <<<nbuk,512,0,stream>>>(ebuf, bbase0, btot, row_start, sorted_src, N, E, shift, nbuk);

    // layer 0: amax known (k_place) -> divide inline
    k_aggregate2<32,true><<<2048,256,0,stream>>>(row_start, sorted_src, ubf, v, e1, e2, fb[0],
                                                 &amax[0], nullptr, nullptr, xA, N);
    // layer 1: 32 -> 64 ; division deferred (exact max via pmax reduce)
    k_xform<32,64><<<(NG*8+3)/4,256,0,stream>>>(xA, fw[1], ww[1], ubf, v, e1, e2, N);
    k_aggregate2<64,false><<<2048,256,0,stream>>>(row_start, sorted_src, ubf, v, e1, e2, fb[1],
                                                  &amax[1], den, pmax, xB, N);
    k_amax<<<128,256,0,stream>>>(pmax, &amax[1], N);
    k_div <<<2048,256,0,stream>>>(xB, den, &amax[1], N);
    // layer 2: 64 -> 64 ; division deferred into pool (fused on load)
    k_xform<64,64><<<(NG*8+3)/4,256,0,stream>>>(xB, fw[2], ww[2], ubf, v, e1, e2, N);
    k_aggregate2<64,false><<<2048,256,0,stream>>>(row_start, sorted_src, ubf, v, e1, e2, fb[2],
                                                  &amax[2], den, pmax, xA, N);
    k_amax<<<128,256,0,stream>>>(pmax, &amax[2], N);

    // pool consumes undivided xA with den/amax[2]
    k_pool1<<<NPOOL,512,0,stream>>>(xA, gid, den, &amax[2], gpart, N);
    k_pool2<<<16,  256,0,stream>>>(gpart, g, NPOOL);
    k_mlp  <<<1,  1024,0,stream>>>(g, mw0, mb0, mw1, mb1, out);
}

// Round 14
// 391.744 us; speedup vs baseline: 1.4066x; 1.0084x over previous
//
#include <hip/hip_runtime.h>
#include <hip/hip_bf16.h>
#include <math.h>

#define NGRAPH 64
#define EPSV 1e-6f
#define CH 4096          // edges per partition chunk

__device__ __forceinline__ unsigned enc_f32(float f){
    unsigned u = __float_as_uint(f);
    return (u & 0x80000000u) ? ~u : (u | 0x80000000u);
}
__device__ __forceinline__ float dec_f32(unsigned u){
    return (u & 0x80000000u) ? __uint_as_float(u & 0x7FFFFFFFu) : __uint_as_float(~u);
}
__device__ __forceinline__ unsigned bf16_rn(float x){
    unsigned u = __float_as_uint(x);
    return (u + 0x7fffu + ((u>>16)&1u)) >> 16;
}
__device__ __forceinline__ float bflo(unsigned u){ return __uint_as_float(u<<16); }
__device__ __forceinline__ float bfhi(unsigned u){ return __uint_as_float(u & 0xffff0000u); }

// ---------------- bucket histogram ----------------
__global__ __launch_bounds__(256) void k_hist_c(const int* __restrict__ tgt,
                                                int* __restrict__ bhist,
                                                int E, int shift, int nbuk){
    __shared__ int h[256];
    int t = threadIdx.x;
    h[t] = 0; __syncthreads();
    int blk = blockIdx.x;            // sub-block: 2048 edges
    int chunk = blk >> 1;
    int base = blk*2048;
    int lim  = base + 2048; if(lim > E) lim = E;
    for(int i=base+t; i<lim; i+=256)
        atomicAdd(&h[tgt[i]>>shift], 1);
    __syncthreads();
    if(t < nbuk && h[t]) atomicAdd(&bhist[chunk*nbuk + t], h[t]);
}

__global__ __launch_bounds__(256) void k_btot(const int* __restrict__ bhist, int* __restrict__ btot,
                                              int nchunk, int nbuk){
    __shared__ int red[256];
    int b = blockIdx.x, t = threadIdx.x;
    int s = 0;
    for(int blk=t; blk<nchunk; blk+=256) s += bhist[blk*nbuk + b];
    red[t] = s; __syncthreads();
    for(int off=128; off>0; off>>=1){
        if(t<off) red[t] += red[t+off];
        __syncthreads();
    }
    if(t==0) btot[b] = red[0];
}

__global__ __launch_bounds__(256) void k_bbase0(const int* __restrict__ btot, int* __restrict__ bbase0, int nbuk){
    __shared__ int s[256];
    int t = threadIdx.x;
    int v = (t<nbuk) ? btot[t] : 0;
    s[t] = v; __syncthreads();
    for(int off=1; off<256; off<<=1){
        int a = (t>=off) ? s[t-off] : 0;
        __syncthreads();
        s[t] += a;
        __syncthreads();
    }
    if(t<nbuk) bbase0[t] = s[t] - v;
}

__global__ __launch_bounds__(512) void k_bbase(const int* __restrict__ bhist, const int* __restrict__ bbase0,
                                               int* __restrict__ bbase, int nchunk, int nbuk){
    __shared__ int s[512];
    int b = blockIdx.x, t = threadIdx.x;
    int v = (t<nchunk) ? bhist[t*nbuk + b] : 0;
    s[t] = v; __syncthreads();
    for(int off=1; off<512; off<<=1){
        int a = (t>=off) ? s[t-off] : 0;
        __syncthreads();
        s[t] += a;
        __syncthreads();
    }
    if(t<nchunk) bbase[t*nbuk + b] = bbase0[b] + s[t] - v;
}

// place edges (packed 32-bit: src<<shift | tgt_local) into bucket-ordered ebuf
// via LDS tickets; fused exact layer-0 edge max of e1*e2
__global__ __launch_bounds__(256) void k_place(const int* __restrict__ src, const int* __restrict__ tgt,
                                               const int* __restrict__ bbase, unsigned* __restrict__ ebuf,
                                               const float* __restrict__ e1, const float* __restrict__ e2,
                                               unsigned* __restrict__ amax_enc,
                                               int E, int shift, int nbuk){
    __shared__ int lcur[256];
    __shared__ float wm[4];
    int t = threadIdx.x, blk = blockIdx.x;
    lcur[t] = (t<nbuk) ? bbase[blk*nbuk + t] : 0;
    __syncthreads();
    unsigned msk = (1u<<shift) - 1u;
    int base = blk*CH;
    int lim  = base + CH; if(lim > E) lim = E;
    float m = 0.f;
    for(int i=base+t; i<lim; i+=256){
        int ss = src[i], tt = tgt[i];
        m = fmaxf(m, e1[ss] * e2[tt]);
        int p = atomicAdd(&lcur[tt>>shift], 1);
        ebuf[p] = ((unsigned)ss << shift) | ((unsigned)tt & msk);
    }
    for(int off=32; off>0; off>>=1) m = fmaxf(m, __shfl_xor(m, off));
    if((t&63)==0) wm[t>>6] = m;
    __syncthreads();
    if(t==0){
        float mm = fmaxf(fmaxf(wm[0],wm[1]), fmaxf(wm[2],wm[3]));
        atomicMax(amax_enc, enc_f32(mm));
    }
}

// per-bucket local CSR from packed ebuf
__global__ __launch_bounds__(512) void k_sortb(const unsigned* __restrict__ ebuf,
                                               const int* __restrict__ bbase0, const int* __restrict__ btot,
                                               int* __restrict__ row_start, int* __restrict__ sorted_src,
                                               int N, int E, int shift, int nbuk){
    __shared__ int sc[512];
    int b = blockIdx.x, t = threadIdx.x;
    int ebeg = bbase0[b];
    int eend = ebeg + btot[b];
    int nbeg = b << shift;
    unsigned msk = (1u<<shift) - 1u;
    int nloc = N - nbeg; if(nloc > 512) nloc = 512;
    sc[t] = 0; __syncthreads();
    for(int i=ebeg+t; i<eend; i+=512)
        atomicAdd(&sc[ebuf[i] & msk], 1);
    __syncthreads();
    int v = sc[t];
    for(int off=1; off<512; off<<=1){
        int a = (t>=off) ? sc[t-off] : 0;
        __syncthreads();
        sc[t] += a;
        __syncthreads();
    }
    int pos0 = ebeg + sc[t] - v;
    if(t < nloc) row_start[nbeg + t] = pos0;
    if(b == nbuk-1 && t == 0) row_start[N] = E;
    __syncthreads();
    sc[t] = pos0;
    __syncthreads();
    for(int i=ebeg+t; i<eend; i+=512){
        unsigned w = ebuf[i];
        int p = atomicAdd(&sc[w & msk], 1);
        sorted_src[p] = (int)(w >> shift);
    }
}

// ---------------- node transform ----------------
// FDIV: input rows are undivided layer outputs -> scale by 1/(den[n]+eps*A) on load.
template<int DI, int DO, bool FDIV>
__global__ __launch_bounds__(256) void k_xform(
    const float* __restrict__ x, const float* __restrict__ fw,
    const float* __restrict__ ww,
    unsigned* __restrict__ ubf, float* __restrict__ v,
    float* __restrict__ e1, float* __restrict__ e2,
    const float* __restrict__ den, const unsigned* __restrict__ amax_enc, int N)
{
    constexpr int NSLICE = 2*DO/16;
    constexpr int CP = DO/2;
    int lane = threadIdx.x & 63;
    int wid  = __builtin_amdgcn_readfirstlane(threadIdx.x >> 6);
    int wg   = blockIdx.x*4 + wid;
    int ngroups = (N+63)>>6;
    if(wg >= ngroups*NSLICE) return;
    int slice = wg % NSLICE;
    int group = wg / NSLICE;
    int n  = group*64 + lane;
    bool act = n < N;
    int nn = act ? n : N-1;
    bool uhalf = slice < DO/16;
    int scol = (slice & (DO/16 - 1))*16;
    const float* wp  = fw + (uhalf ? 0 : DI*DO) + scol;
    const float* wwp = ww + (uhalf ? 0 : DI);
    float r = 1.f;
    if(FDIV) r = 1.f/(den[nn] + EPSV*dec_f32(*amax_enc));
    float acc[16];
    #pragma unroll
    for(int j=0;j<16;j++) acc[j]=0.f;
    float p = 0.f;
    #pragma unroll
    for(int k4=0;k4<DI/4;k4++){
        float4 xv = *reinterpret_cast<const float4*>(&x[(size_t)nn*DI + k4*4]);
        if(FDIV){ xv.x*=r; xv.y*=r; xv.z*=r; xv.w*=r; }
        #pragma unroll
        for(int kk=0;kk<4;kk++){
            float xk = (kk==0)?xv.x:(kk==1)?xv.y:(kk==2)?xv.z:xv.w;
            int k = k4*4+kk;
            p = fmaf(xk, wwp[k], p);
            #pragma unroll
            for(int j=0;j<16;j++) acc[j] = fmaf(xk, wp[k*DO + j], acc[j]);
        }
    }
    if(act){
        if(uhalf){
            unsigned pk[8];
            #pragma unroll
            for(int j=0;j<8;j++)
                pk[j] = bf16_rn(acc[2*j]) | (bf16_rn(acc[2*j+1])<<16);
            unsigned* dst = &ubf[(size_t)n*CP + scol/2];
            *reinterpret_cast<uint4*>(dst)   = make_uint4(pk[0],pk[1],pk[2],pk[3]);
            *reinterpret_cast<uint4*>(dst+4) = make_uint4(pk[4],pk[5],pk[6],pk[7]);
        } else {
            #pragma unroll
            for(int j4=0;j4<4;j4++)
                *reinterpret_cast<float4*>(&v[(size_t)n*DO + scol + j4*4]) =
                    make_float4(acc[j4*4],acc[j4*4+1],acc[j4*4+2],acc[j4*4+3]);
        }
        if(scol==0) (uhalf ? e1 : e2)[n] = __expf(p);
    }
}

// ---------------- edge softmax + aggregate: lane = channel PAIR ----------------
// DIV=true  (layer 0): amax already known -> divide inline.
// DIV=false (layers 1,2): write num (xout), den[n], pmax[n]; k_amax reduces
//   the exact global edge-max A = max_n pmax[n]; division deferred to consumer.
// NOTE: no global atomics in this kernel (single-address atomicMax = +80us, R12).
template<int DO, bool DIV>
__global__ __launch_bounds__(256) void k_aggregate2(
    const int* __restrict__ row_start, const int* __restrict__ sorted_src,
    const unsigned* __restrict__ ubf, const float* __restrict__ v,
    const float* __restrict__ e1, const float* __restrict__ e2,
    const float* __restrict__ fb,
    const unsigned* __restrict__ amax_enc,
    float* __restrict__ den_out, float* __restrict__ pmax_out,
    float* __restrict__ xout, int N)
{
    constexpr int CP = DO/2;
    constexpr int PN = 64/CP;
    float epsA = 0.f;
    if(DIV) epsA = EPSV * dec_f32(*amax_enc);
    int lane = threadIdx.x & 63;
    int wid  = threadIdx.x >> 6;
    int c2   = lane & (CP-1);
    int grp  = lane >> (CP==32 ? 5 : 4);
    float fx = fb[2*c2], fy = fb[2*c2+1];
    int gw = blockIdx.x*4 + wid;
    int nwaves = gridDim.x*4;
    for(int n=gw; n<N; n+=nwaves){
        float2 vv = *reinterpret_cast<const float2*>(&v[(size_t)n*DO + 2*c2]);
        float wx = vv.x + fx, wy = vv.y + fy;
        float e2n = e2[n];
        int beg = row_start[n], end = row_start[n+1];
        float ax = 0.f, ay = 0.f, den = 0.f, pm = 0.f;
        int idx = beg + grp;
        for(; idx + 7*PN < end; idx += 8*PN){
            int s_[8]; float e_[8]; unsigned u_[8];
            #pragma unroll
            for(int q=0;q<8;q++) s_[q] = sorted_src[idx+q*PN];
            #pragma unroll
            for(int q=0;q<8;q++){ e_[q] = e1[s_[q]]; u_[q] = ubf[(size_t)s_[q]*CP+c2]; }
            #pragma unroll
            for(int q=0;q<8;q++){
                float p = e_[q]*e2n;
                den += p;
                if(!DIV) pm = fmaxf(pm, p);
                ax = fmaf(p, fmaxf(bflo(u_[q])+wx,0.f), ax);
                ay = fmaf(p, fmaxf(bfhi(u_[q])+wy,0.f), ay);
            }
        }
        for(; idx + 3*PN < end; idx += 4*PN){
            int s_[4]; float e_[4]; unsigned u_[4];
            #pragma unroll
            for(int q=0;q<4;q++) s_[q] = sorted_src[idx+q*PN];
            #pragma unroll
            for(int q=0;q<4;q++){ e_[q] = e1[s_[q]]; u_[q] = ubf[(size_t)s_[q]*CP+c2]; }
            #pragma unroll
            for(int q=0;q<4;q++){
                float p = e_[q]*e2n;
                den += p;
                if(!DIV) pm = fmaxf(pm, p);
                ax = fmaf(p, fmaxf(bflo(u_[q])+wx,0.f), ax);
                ay = fmaf(p, fmaxf(bfhi(u_[q])+wy,0.f), ay);
            }
        }
        for(; idx < end; idx += PN){
            int s = sorted_src[idx];
            float e = e1[s];
            unsigned uu = ubf[(size_t)s*CP+c2];
            float p = e*e2n;
            den += p;
            if(!DIV) pm = fmaxf(pm, p);
            ax = fmaf(p, fmaxf(bflo(uu)+wx,0.f), ax);
            ay = fmaf(p, fmaxf(bfhi(uu)+wy,0.f), ay);
        }
        #pragma unroll
        for(int off=CP; off<64; off<<=1){
            den += __shfl_xor(den, off);
            ax  += __shfl_xor(ax , off);
            ay  += __shfl_xor(ay , off);
            if(!DIV) pm = fmaxf(pm, __shfl_xor(pm, off));
        }
        if(DIV){
            if(lane < CP){
                float d = den + epsA;
                *reinterpret_cast<float2*>(&xout[(size_t)n*DO + 2*c2]) =
                    make_float2(ax/d, ay/d);
            }
        } else {
            if(lane < CP)
                *reinterpret_cast<float2*>(&xout[(size_t)n*DO + 2*c2]) =
                    make_float2(ax, ay);
            if(lane == 0){ den_out[n] = den; pmax_out[n] = pm; }
        }
    }
}

// reduce max over pmax[N] -> amax_enc
__global__ __launch_bounds__(256) void k_amax(const float* __restrict__ pmax,
                                              unsigned* __restrict__ amax_enc, int N){
    __shared__ float wm[4];
    float m = 0.f;
    for(int i = blockIdx.x*256 + threadIdx.x; i<N; i += gridDim.x*256)
        m = fmaxf(m, pmax[i]);
    for(int off=32; off>0; off>>=1) m = fmaxf(m, __shfl_xor(m, off));
    if((threadIdx.x&63)==0) wm[threadIdx.x>>6] = m;
    __syncthreads();
    if(threadIdx.x==0)
        atomicMax(amax_enc, enc_f32(fmaxf(fmaxf(wm[0],wm[1]), fmaxf(wm[2],wm[3]))));
}

// ---------------- graph pooling (fused layer-2 division on load) ----------------
__global__ __launch_bounds__(512) void k_pool1(const float* __restrict__ x, const int* __restrict__ gid,
                                               const float* __restrict__ den, const unsigned* __restrict__ amax_enc,
                                               float* __restrict__ gpart, int N){
    __shared__ float bins[64*64];
    float epsA = EPSV * dec_f32(*amax_enc);
    int t = threadIdx.x;
    for(int i=t;i<4096;i+=512) bins[i]=0.f;
    __syncthreads();
    int lane = t & 63, wid = t>>6;
    int gw = blockIdx.x*8 + wid;
    int nwaves = gridDim.x*8;
    for(int n=gw; n<N; n+=nwaves){
        int gi = gid[n];
        float r = 1.f/(den[n] + epsA);
        atomicAdd(&bins[gi*64 + lane], x[(size_t)n*64 + lane]*r);
    }
    __syncthreads();
    float* dst = &gpart[(size_t)blockIdx.x*4096];
    for(int i=t;i<4096;i+=512) dst[i] = bins[i];
}

__global__ __launch_bounds__(256) void k_pool2(const float* __restrict__ gpart, float* __restrict__ g, int nblk){
    int i = blockIdx.x*256 + threadIdx.x;   // i < 4096
    float s0=0.f, s1=0.f, s2=0.f, s3=0.f;
    int k=0;
    for(; k+3<nblk; k+=4){
        s0 += gpart[(size_t)k*4096+i];
        s1 += gpart[(size_t)(k+1)*4096+i];
        s2 += gpart[(size_t)(k+2)*4096+i];
        s3 += gpart[(size_t)(k+3)*4096+i];
    }
    for(; k<nblk; k++) s0 += gpart[(size_t)k*4096+i];
    g[i] = (s0+s1)+(s2+s3);
}

// ---------------- tiny MLP head ----------------
__global__ __launch_bounds__(1024) void k_mlp(const float* __restrict__ g,
        const float* __restrict__ mw0, const float* __restrict__ mb0,
        const float* __restrict__ mw1, const float* __restrict__ mb1,
        float* __restrict__ out){
    __shared__ float lg[64*64];
    __shared__ float hid[64*32];
    int t = threadIdx.x;
    for(int i=t;i<4096;i+=1024) lg[i]=g[i];
    __syncthreads();
    for(int i=t;i<2048;i+=1024){
        int r = i>>5, h = i&31;
        float a = mb0[h];
        for(int k=0;k<64;k++) a = fmaf(lg[r*64+k], mw0[k*32+h], a);
        hid[i] = fmaxf(a, 0.f);
    }
    __syncthreads();
    for(int i=t;i<640;i+=1024){
        int r = i/10, j = i%10;
        float a = mb1[j];
        for(int h=0;h<32;h++) a = fmaf(hid[r*32+h], mw1[h*10+j], a);
        out[i] = a;
    }
}

extern "C" void kernel_launch(void* const* d_in, const int* in_sizes, int n_in,
                              void* d_out, int out_size, void* d_ws, size_t ws_size,
                              hipStream_t stream){
    const float* x   = (const float*)d_in[0];
    const int*   src = (const int*)d_in[1];
    const int*   tgt = (const int*)d_in[2];
    const int*   gid = (const int*)d_in[3];
    const float* fw[3] = {(const float*)d_in[4],  (const float*)d_in[8],  (const float*)d_in[12]};
    const float* fb[3] = {(const float*)d_in[5],  (const float*)d_in[9],  (const float*)d_in[13]};
    const float* ww[3] = {(const float*)d_in[6],  (const float*)d_in[10], (const float*)d_in[14]};
    const float* mw0 = (const float*)d_in[16];
    const float* mb0 = (const float*)d_in[17];
    const float* mw1 = (const float*)d_in[18];
    const float* mb1 = (const float*)d_in[19];
    float* out = (float*)d_out;

    const int N = in_sizes[3];
    const int E = in_sizes[1];
    const int NG = (N + 63)/64;
    const int NCHUNK = (E + CH - 1)/CH;
    const int NPOOL = 512;
    int shift = 0;
    while(((N-1)>>shift) >= 256) shift++;        // 512 nodes/bucket, nbuk<=256
    const int nbuk = ((N-1)>>shift) + 1;

    char* ws = (char*)d_ws;
    size_t off = 0;
    auto alloc = [&](size_t bytes)->char*{
        char* p = ws + off;
        off += (bytes + 255) & ~(size_t)255;
        return p;
    };
    int*      row_start  = (int*)     alloc((size_t)(N+1)*4);
    int*      sorted_src = (int*)     alloc((size_t)E*4);
    unsigned* ebuf       = (unsigned*)alloc((size_t)E*4);
    float*    e1         = (float*)   alloc((size_t)N*4);
    float*    e2         = (float*)   alloc((size_t)N*4);
    float*    den        = (float*)   alloc((size_t)N*4);
    float*    pmax       = (float*)   alloc((size_t)N*4);
    unsigned* ubf        = (unsigned*)alloc((size_t)N*32*4);
    float*    v          = (float*)   alloc((size_t)N*64*4);
    float*    xA         = (float*)   alloc((size_t)N*64*4);
    float*    xB         = (float*)   alloc((size_t)N*64*4);
    unsigned* amax       = (unsigned*)alloc(3*4);
    float*    g          = (float*)   alloc(4096*4);
    float*    gpart      = (float*)   alloc((size_t)NPOOL*4096*4);
    int*      bhist      = (int*)     alloc((size_t)NCHUNK*nbuk*4);
    int*      btot       = (int*)     alloc(256*4);
    int*      bbase0     = (int*)     alloc(256*4);
    int*      bbase      = (int*)     alloc((size_t)NCHUNK*nbuk*4);

    hipMemsetAsync(amax,  0, 12, stream);
    hipMemsetAsync(bhist, 0, (size_t)NCHUNK*nbuk*4, stream);

    // layer-0 transform first: e1/e2 ready for fused edge-max inside k_place
    k_xform<64,32,false><<<(NG*4+3)/4,256,0,stream>>>(x, fw[0], ww[0], ubf, v, e1, e2, nullptr, nullptr, N);

    k_hist_c <<<NCHUNK*2,256,0,stream>>>(tgt, bhist, E, shift, nbuk);
    k_btot   <<<nbuk,256,0,stream>>>(bhist, btot, NCHUNK, nbuk);
    k_bbase0 <<<1,   256,0,stream>>>(btot, bbase0, nbuk);
    k_bbase  <<<nbuk,512,0,stream>>>(bhist, bbase0, bbase, NCHUNK, nbuk);
    k_place  <<<NCHUNK,256,0,stream>>>(src, tgt, bbase, ebuf, e1, e2, &amax[0], E, shift, nbuk);
    k_sortb  <<<nbuk,512,0,stream>>>(ebuf, bbase0, btot, row_start, sorted_src, N, E, shift, nbuk);

    // layer 0: amax known (k_place) -> divide inline
    k_aggregate2<32,true><<<2048,256,0,stream>>>(row_start, sorted_src, ubf, v, e1, e2, fb[0],
                                                 &amax[0], nullptr, nullptr, xA, N);
    // layer 1: 32 -> 64 ; division deferred into layer-2 xform (exact max via pmax reduce)
    k_xform<32,64,false><<<(NG*8+3)/4,256,0,stream>>>(xA, fw[1], ww[1], ubf, v, e1, e2, nullptr, nullptr, N);
    k_aggregate2<64,false><<<2048,256,0,stream>>>(row_start, sorted_src, ubf, v, e1, e2, fb[1],
                                                  &amax[1], den, pmax, xB, N);
    k_amax<<<128,256,0,stream>>>(pmax, &amax[1], N);
    // layer 2: 64 -> 64 ; xform consumes undivided xB (FDIV), division into pool for its output
    k_xform<64,64,true><<<(NG*8+3)/4,256,0,stream>>>(xB, fw[2], ww[2], ubf, v, e1, e2, den, &amax[1], N);
    k_aggregate2<64,false><<<2048,256,0,stream>>>(row_start, sorted_src, ubf, v, e1, e2, fb[2],
                                                  &amax[2], den, pmax, xA, N);
    k_amax<<<128,256,0,stream>>>(pmax, &amax[2], N);

    // pool consumes undivided xA with den/amax[2]
    k_pool1<<<NPOOL,512,0,stream>>>(xA, gid, den, &amax[2], gpart, N);
    k_pool2<<<16,  256,0,stream>>>(gpart, g, NPOOL);
    k_mlp  <<<1,  1024,0,stream>>>(g, mw0, mb0, mw1, mb1, out);
}